// Round 1
// baseline (207.249 us; speedup 1.0000x reference)
//
#include <hip/hip_runtime.h>

typedef unsigned short u16;
typedef unsigned int   u32;

using bf16x8 = __attribute__((ext_vector_type(8))) __bf16;
using f32x4  = __attribute__((ext_vector_type(4))) float;
using f32x16 = __attribute__((ext_vector_type(16))) float;

#define DEV static __device__ __forceinline__
#define GP(p) (const __attribute__((address_space(1))) void*)(p)
#define LP(p) (__attribute__((address_space(3))) void*)(p)
// fused counted-wait + barrier (T4): memory clobber pins LDS/global ops on both sides
#define WAITB(N) asm volatile("s_waitcnt vmcnt(" N ")\n\ts_barrier" ::: "memory")
#define BARR  asm volatile("s_barrier" ::: "memory")
#define LGKM0 asm volatile("s_waitcnt lgkmcnt(0)" ::: "memory")

DEV u16 f2bf(float f){                      // RNE float->bf16
  u32 u = __builtin_bit_cast(u32, f);
  u32 r = u + 0x7fffu + ((u>>16)&1u);
  return (u16)(r>>16);
}
DEV bf16x8 as_bf(uint4 v){ return __builtin_bit_cast(bf16x8, v); }
DEV u32 cvt_pk(float lo, float hi){
  u32 r;
  asm("v_cvt_pk_bf16_f32 %0, %1, %2" : "=v"(r) : "v"(lo), "v"(hi));
  return r;
}
DEV void plswap(u32 &a, u32 &b){
  auto r = __builtin_amdgcn_permlane32_swap((int)a, (int)b, false, false);
  a = (u32)r[0]; b = (u32)r[1];
}
DEV float fexp2(float x){ float r; asm("v_exp_f32 %0, %1" : "=v"(r) : "v"(x)); return r; }
DEV float max3f(float a, float b, float c){
  float r; asm("v_max3_f32 %0, %1, %2, %3" : "=v"(r) : "v"(a), "v"(b), "v"(c)); return r;
}

// problem constants
constexpr int CB = 4, CL = 2048, CE = 1024, CH = 16, CD = 64;
constexpr int CM = CB*CL;           // 8192 rows
constexpr float LOG2E  = 1.44269504088896f;
constexpr float NEGBIG = -1.44269504e9f;    // -1e9 * log2e (exp2 domain)

// ---------------- mask dtype detection ----------------
__global__ void detect_mask_kernel(const void* __restrict__ mask, int* __restrict__ flag){
  __shared__ int a_gt1, a_badf, a_oddnz, a_evennz;
  if (threadIdx.x==0){ a_gt1=0; a_badf=0; a_oddnz=0; a_evennz=0; }
  __syncthreads();
  const u32* w = (const u32*)mask;
  int gt1=0, badf=0, oddnz=0, evennz=0;
  for (int i=threadIdx.x; i<2048; i+=256){
    u32 v = w[i];
    if (v > 1u) gt1 = 1;
    if (v != 0u && v != 0x3f800000u) badf = 1;
    if (v != 0u){ if (i & 1) oddnz = 1; else evennz = 1; }
  }
  if (gt1) atomicOr(&a_gt1,1);
  if (badf) atomicOr(&a_badf,1);
  if (oddnz) atomicOr(&a_oddnz,1);
  if (evennz) atomicOr(&a_evennz,1);
  __syncthreads();
  if (threadIdx.x==0){
    int mode;
    if (!a_gt1)           mode = (!a_oddnz && a_evennz) ? 3 : 0;
    else if (!a_badf)     mode = 1;
    else                  mode = 2;
    flag[0] = mode;
  }
}

__global__ void convert_mask_kernel(const void* __restrict__ mask, const int* __restrict__ flag,
                                    float* __restrict__ maskf){
  int i = blockIdx.x*blockDim.x + threadIdx.x;   // B*L
  if (i >= CB*CL) return;
  int mode = flag[0];
  int v;
  if      (mode==0) v = ((const int*)mask)[i] != 0;
  else if (mode==1) v = ((const float*)mask)[i] != 0.f;
  else if (mode==3) v = ((const int*)mask)[2*i] != 0;
  else              v = ((const unsigned char*)mask)[i] != 0;
  maskf[i] = v ? NEGBIG : 0.f;
}

// ---------------- all fp32 -> bf16 casts, one launch ----------------
__global__ void cast_all(const float* __restrict__ q, const float* __restrict__ k,
                         const float* __restrict__ v,
                         const float* __restrict__ wq, const float* __restrict__ wk,
                         const float* __restrict__ wv, const float* __restrict__ wo,
                         u16* __restrict__ oq, u16* __restrict__ ok, u16* __restrict__ ov,
                         u16* __restrict__ owq, u16* __restrict__ owk,
                         u16* __restrict__ owv, u16* __restrict__ owo){
  int i = blockIdx.x*blockDim.x + threadIdx.x;   // 7*2^20 float4 items
  const float* in; u16* out; int j;
  if (i < 3*(1<<21)){
    int w = i >> 21; j = i & ((1<<21)-1);
    in = (w==0)?q:(w==1)?k:v; out = (w==0)?oq:(w==1)?ok:ov;
  } else {
    int r = i - 3*(1<<21);
    int w = r >> 18; j = r & ((1<<18)-1);
    in = (w==0)?wq:(w==1)?wk:(w==2)?wv:wo; out = (w==0)?owq:(w==1)?owk:(w==2)?owv:owo;
  }
  float4 a = ((const float4*)in)[j];
  ushort4 h;
  h.x = f2bf(a.x); h.y = f2bf(a.y); h.z = f2bf(a.z); h.w = f2bf(a.w);
  ((ushort4*)out)[j] = h;
}

// ---------------- QKV projection GEMM: 256^2 tile, 8-wave, 8-phase counted-vmcnt ----------------
// T3+T4 template (learn_hip m196-m218): 2 K-tile LDS double buffer (128 KiB), BK=64,
// 8 phases/iter (= 2 K-tiles), 16 MFMA per phase (one 128x128 C-quadrant x K=64),
// vmcnt(4) only at phases 4 and 8, setprio(1) around each MFMA cluster (T5).
// LDS swizzle: 16B-chunk ^= row&7 both-sides (this kernel's own proven 0-conflict variant).
//
// z=0: Q = qbf@wq^T+bq, scaled 0.125*log2e, RoPE, pack [B,H,L,D]
// z=1: K = kbf@wk^T+bk, RoPE, pack [B,H,L,D]
// z=2: Vt = (wvb@vbf^T)+bv[row], bf16 [E][CM] (pre-transposed V)
//
// Wave map: 8 waves; per 128x128 quadrant a 4M x 2N wave grid (32x64 each), so a wave's
// 128 output cols = whole heads (needed by the RoPE epilogue pairing nr <-> nr+2).
//
// Stage slots (half-tile = 128 rows x 64 k = 2 gload_lds/thread), one per phase:
//   ph1:(T+1)A1  ph2:(T+1)B0  ph3:(T+2)A0  ph4:(T+2)B1
//   ph5:(T+2)A1  ph6:(T+2)B0  ph7:(T+3)A0  ph8:(T+3)B1
// Reader phases (per tile): A0:ph1  B1:ph2  A1:ph3  B0:ph1+ph4  -> every slot lands one
// phase after its target half's last read (post-barrier), so no write-under-read race.
// Ledger: at ph4/ph8 barrier 12 loads outstanding, wait vmcnt(4) -> next tile complete,
// 2 half-tiles (4 loads) stay in flight. Prologue: tile0 (8) + t1:A0,B1 (4), WAITB(4).

#define STAGE_A(T,BUF,H) do{ \
  const u16* _s = Abase + (size_t)(m0 + (H)*128)*CE + (T)*64; \
  u16* _d = &As[BUF][(H)*8192]; \
  _Pragma("unroll") \
  for (int _i=0;_i<2;_i++){ \
    int _c = tid + _i*512; int _row = _c>>3; int _sc = (_c&7) ^ (_row&7); \
    __builtin_amdgcn_global_load_lds(GP(_s + (size_t)_row*CE + _sc*8), LP(_d + _c*8), 16, 0, 0); \
  } \
}while(0)

#define STAGE_B(T,BUF,H) do{ \
  const u16* _s = Btbase + (size_t)(n0 + (H)*128)*CE + (T)*64; \
  u16* _d = &Bs[BUF][(H)*8192]; \
  _Pragma("unroll") \
  for (int _i=0;_i<2;_i++){ \
    int _c = tid + _i*512; int _row = _c>>3; int _sc = (_c&7) ^ (_row&7); \
    __builtin_amdgcn_global_load_lds(GP(_s + (size_t)_row*CE + _sc*8), LP(_d + _c*8), 16, 0, 0); \
  } \
}while(0)

#define RD_A(BUF,QM) do{ \
  const char* _p = (const char*)As[BUF] + ((QM)*128 + wrr*32 + llo)*128; \
  _Pragma("unroll") \
  for (int _mr=0;_mr<2;_mr++) \
    _Pragma("unroll") \
    for (int _ks=0;_ks<2;_ks++) \
      af[_mr*2+_ks] = as_bf(*(const uint4*)(_p + _mr*2048 + ((((_ks<<2)+lhi)^rsw)<<4))); \
}while(0)

#define RD_B(BUF,QN) do{ \
  const char* _p = (const char*)Bs[BUF] + ((QN)*128 + wcc*64 + llo)*128; \
  _Pragma("unroll") \
  for (int _nr=0;_nr<4;_nr++) \
    _Pragma("unroll") \
    for (int _ks=0;_ks<2;_ks++) \
      bfr[_nr*2+_ks] = as_bf(*(const uint4*)(_p + _nr*2048 + ((((_ks<<2)+lhi)^rsw)<<4))); \
}while(0)

#define MM(QM,QN) do{ \
  __builtin_amdgcn_s_setprio(1); \
  _Pragma("unroll") \
  for (int _mr=0;_mr<2;_mr++) \
    _Pragma("unroll") \
    for (int _nr=0;_nr<4;_nr++){ \
      acc[QM][QN][_mr][_nr] = __builtin_amdgcn_mfma_f32_16x16x32_bf16(af[_mr*2+0], bfr[_nr*2+0], acc[QM][QN][_mr][_nr], 0,0,0); \
      acc[QM][QN][_mr][_nr] = __builtin_amdgcn_mfma_f32_16x16x32_bf16(af[_mr*2+1], bfr[_nr*2+1], acc[QM][QN][_mr][_nr], 0,0,0); \
    } \
  __builtin_amdgcn_s_setprio(0); \
}while(0)

__global__ __launch_bounds__(512,2) void gemm_qkv(
    const u16* __restrict__ qbf, const u16* __restrict__ kbf, const u16* __restrict__ vbf,
    const u16* __restrict__ wqb, const u16* __restrict__ wkb, const u16* __restrict__ wvb,
    const float* __restrict__ bq, const float* __restrict__ bk, const float* __restrict__ bv,
    u16* __restrict__ Qp, u16* __restrict__ Kp, u16* __restrict__ Vt, int zbase)
{
  __shared__ u16 As[2][16384];   // [buf][256 rows][64 k], 16B-chunk swizzled, halves of 128 rows
  __shared__ u16 Bs[2][16384];
  const int z = zbase + blockIdx.y;
  const int tid=threadIdx.x, lane=tid&63, wid=tid>>6;
  const int llo=lane&15, lhi=lane>>4;
  const int wrr=wid>>1, wcc=wid&1;       // 4M x 2N wave grid inside each quadrant
  const int rsw = llo&7;
  const u16* Abase; const u16* Btbase;
  if (z==0){ Abase=qbf; Btbase=wqb; }
  else if (z==1){ Abase=kbf; Btbase=wkb; }
  else { Abase=wvb; Btbase=vbf; }
  // XCD supertile: group the 4 blocks sharing one 256-row A panel (z<2) / B panel (z=2)
  // on the same XCD: working set ~4MB = one XCD L2.
  int bid = blockIdx.x;                  // 0..127 per z
  int xcd = bid&7, jj = bid>>3;          // jj in [0,16)
  int mb, nb;
  if (z<2){ mb = xcd*4 + (jj>>2); nb = jj&3; }   // 32 x 4 tiles
  else    { mb = jj&3; nb = xcd*4 + (jj>>2); }   // 4 x 32 tiles
  const int m0 = mb*256, n0 = nb*256;

  f32x4 acc[2][2][2][4] = {};            // [qm][qn][mr][nr], 128 VGPR
  bf16x8 af[4], bfr[8];

  // prologue: tile0 complete + tile1 {A0,B1} in flight
  STAGE_A(0,0,0); STAGE_A(0,0,1); STAGE_B(0,0,0); STAGE_B(0,0,1);
  STAGE_A(1,1,0); STAGE_B(1,1,1);
  WAITB("4");

  // 16 K-tiles of 64; iteration = 2 tiles (bufs 0,1); last iteration peeled.
  #pragma unroll 1
  for (int j=0;j<7;j++){
    const int T = 2*j;
    // ph1 (0,0): tile T
    RD_A(0,0); RD_B(0,0);
    STAGE_A(T+1,1,1);
    BARR; LGKM0; MM(0,0); BARR;
    // ph2 (0,1): reuse af
    RD_B(0,1);
    STAGE_B(T+1,1,0);
    BARR; LGKM0; MM(0,1); BARR;
    // ph3 (1,1): reuse bfr
    RD_A(0,1);
    STAGE_A(T+2,0,0);
    BARR; LGKM0; MM(1,1); BARR;
    // ph4 (1,0)
    RD_B(0,0);
    STAGE_B(T+2,0,1);
    BARR; LGKM0; MM(1,0);
    WAITB("4");                          // tile T+1 landed; T+2:{A0,B1} in flight
    // ph5 (0,0): tile T+1
    RD_A(1,0); RD_B(1,0);
    STAGE_A(T+2,0,1);
    BARR; LGKM0; MM(0,0); BARR;
    // ph6 (0,1)
    RD_B(1,1);
    STAGE_B(T+2,0,0);
    BARR; LGKM0; MM(0,1); BARR;
    // ph7 (1,1)
    RD_A(1,1);
    STAGE_A(T+3,1,0);
    BARR; LGKM0; MM(1,1); BARR;
    // ph8 (1,0)
    RD_B(1,0);
    STAGE_B(T+3,1,1);
    BARR; LGKM0; MM(1,0);
    WAITB("4");                          // tile T+2 landed; T+3:{A0,B1} in flight
  }
  {ated: // tail iteration (tiles 14,15): only T+1 stages remain
    const int T = 14;
    RD_A(0,0); RD_B(0,0);
    STAGE_A(T+1,1,1);
    BARR; LGKM0; MM(0,0); BARR;
    RD_B(0,1);
    STAGE_B(T+1,1,0);
    BARR; LGKM0; MM(0,1); BARR;
    RD_A(0,1);
    BARR; LGKM0; MM(1,1); BARR;
    RD_B(0,0);
    BARR; LGKM0; MM(1,0);
    WAITB("0");                          // drain: tile 15 fully landed
    RD_A(1,0); RD_B(1,0);
    BARR; LGKM0; MM(0,0); BARR;
    RD_B(1,1);
    BARR; LGKM0; MM(0,1); BARR;
    RD_A(1,1);
    BARR; LGKM0; MM(1,1); BARR;
    RD_B(1,0);
    BARR; LGKM0; MM(1,0);
    // no trailing barrier: epilogue touches no LDS
  }

  // C frag mapping: row = m0 + qm*128 + wrr*32 + mr*16 + lhi*4 + rr
  //                 col = n0 + qn*128 + wcc*64 + nr*16 + llo
  if (z < 2){
    const float* bias = z ? bk : bq;
    u16* outp = z ? Kp : Qp;
    const float scale = z ? 1.f : 0.125f*LOG2E;
    float b1[2][2], b2[2][2], invf[2];
    #pragma unroll
    for (int nr=0;nr<2;nr++){
      int j2 = nr*16 + llo;
      invf[nr] = exp2f(-(float)j2 * 0.41524101186092033f);   // 10000^{-j2/32}
      #pragma unroll
      for (int qn=0;qn<2;qn++){
        int cb = n0 + qn*128 + wcc*64 + j2;
        b1[qn][nr] = bias[cb];
        b2[qn][nr] = bias[cb + 32];
      }
    }
    #pragma unroll
    for (int qm=0;qm<2;qm++)
      #pragma unroll
      for (int mr=0;mr<2;mr++)
        #pragma unroll
        for (int rr=0;rr<4;rr++){
          int row = m0 + qm*128 + wrr*32 + mr*16 + lhi*4 + rr;
          int b = row >> 11, l = row & 2047;
          #pragma unroll
          for (int qn=0;qn<2;qn++){
            int h = (n0>>6) + qn*2 + wcc;           // wave covers whole heads
            u16* dst = outp + (((size_t)(b*CH + h)*CL + l) << 6);
            #pragma unroll
            for (int nr=0;nr<2;nr++){
              int j2 = nr*16 + llo;
              float x1 = (acc[qm][qn][mr][nr][rr]   + b1[qn][nr]) * scale;
              float x2 = (acc[qm][qn][mr][nr+2][rr] + b2[qn][nr]) * scale;
              float ang = (float)l * invf[nr];
              float sn, cs; __sincosf(ang, &sn, &cs);
              dst[j2]      = f2bf(x1*cs - x2*sn);
              dst[j2 + 32] = f2bf(x2*cs + x1*sn);
            }
          }
        }
  } else {
    #pragma unroll
    for (int qm=0;qm<2;qm++)
      #pragma unroll
      for (int mr=0;mr<2;mr++)
        #pragma unroll
        for (int rr=0;rr<4;rr++){
          int row = m0 + qm*128 + wrr*32 + mr*16 + lhi*4 + rr;
          float bvv = bv[row];
          #pragma unroll
          for (int qn=0;qn<2;qn++)
            #pragma unroll
            for (int nr=0;nr<4;nr++){
              int col = n0 + qn*128 + wcc*64 + nr*16 + llo;
              Vt[(size_t)row*CM + col] = f2bf(acc[qm][qn][mr][nr][rr] + bvv);
            }
        }
  }
}

#undef STAGE_A
#undef STAGE_B
#undef RD_A
#undef RD_B
#undef MM

// ---------------- output projection GEMM (fp32 out, bias per col) ----------------
__global__ __launch_bounds__(256) void gemm_out(
    const u16* __restrict__ A, const u16* __restrict__ Bt,
    const float* __restrict__ bias, float* __restrict__ C)
{
  __shared__ u16 As[2][8192];
  __shared__ u16 Bs[2][8192];
  const int tid=threadIdx.x, lane=tid&63, wid=tid>>6;
  const int llo=lane&15, lhi=lane>>4;
  int bid = blockIdx.x;
  int xcd = bid&7, j = bid>>3;
  const int m0 = (xcd*8 + (j>>3))*128, n0 = (j&7)*128;   // Mb=64, Nb=8
  const int wr = wid>>1, wc = wid&1;
  const int rswA = llo&7;

  auto STAGE = [&](int kt, int buf){
    #pragma unroll
    for (int i=0;i<4;i++){
      int c = tid + i*256;
      int row = c>>3, ch = c&7;
      int sc = ch ^ (row&7);
      __builtin_amdgcn_global_load_lds(GP(A  + (size_t)(m0+row)*CE + kt + sc*8),
                                       LP(&As[buf][c*8]), 16, 0, 0);
      __builtin_amdgcn_global_load_lds(GP(Bt + (size_t)(n0+row)*CE + kt + sc*8),
                                       LP(&Bs[buf][c*8]), 16, 0, 0);
    }
  };

  f32x4 acc[4][4] = {};
  STAGE(0, 0);
  asm volatile("s_waitcnt vmcnt(0)" ::: "memory");
  __syncthreads();

  for (int t=0; t<16; t++){
    if (t<15) STAGE((t+1)*64, (t+1)&1);
    const char* as = (const char*)As[t&1];
    const char* bs = (const char*)Bs[t&1];
    #pragma unroll
    for (int ks=0; ks<2; ks++){
      bf16x8 af[4], bf_[4];
      #pragma unroll
      for (int mr=0;mr<4;mr++){
        int r = wr*64+mr*16+llo;
        af[mr] = as_bf(*(const uint4*)(as + r*128 + (((ks*4+lhi)^rswA)<<4)));
      }
      #pragma unroll
      for (int nr=0;nr<4;nr++){
        int r = wc*64+nr*16+llo;
        bf_[nr] = as_bf(*(const uint4*)(bs + r*128 + (((ks*4+lhi)^rswA)<<4)));
      }
      #pragma unroll
      for (int mr=0;mr<4;mr++)
        #pragma unroll
        for (int nr=0;nr<4;nr++)
          acc[mr][nr] = __builtin_amdgcn_mfma_f32_16x16x32_bf16(af[mr], bf_[nr], acc[mr][nr], 0,0,0);
    }
    WAITB("0");
  }

  #pragma unroll
  for (int mr=0;mr<4;mr++)
    #pragma unroll
    for (int nr=0;nr<4;nr++)
      #pragma unroll
      for (int r=0;r<4;r++){
        int row = m0 + wr*64 + mr*16 + lhi*4 + r;
        int col = n0 + wc*64 + nr*16 + llo;
        C[(size_t)row*CE + col] = acc[mr][nr][r] + bias[col];
      }
}

// ---------------- flash attention, swapped-operand 32x32, counted-vmcnt ring ----------------
// Qp,Kp: [B*H, L, D] bf16 (Q pre-scaled by 0.125*log2e). Vt: [E, CM] bf16. Out AO [B,L,E] bf16.
// grid (64 bh, 8 slot): bid%8 = bh%8 -> one XCD serves 8 bh (K/V L2 reuse).
// Block = q-tiles {15-slot, slot} (uniform 34 KV tiles), 4 waves x 32 q.
// Softmax in exp2 domain; defer-max (THR=12 log2 units, p <= 2^12).
__global__ __launch_bounds__(256,2) void attn_kernel(
    const u16* __restrict__ Qp, const u16* __restrict__ Kp, const u16* __restrict__ Vt,
    const float* __restrict__ maskf, u16* __restrict__ AO)
{
  __shared__ u16 K_lds[4][4096];   // ring of [kv64][d64] swizzled tiles
  __shared__ u16 V_lds[4][4096];   // ring of [d64][kv64] swizzled tiles
  __shared__ float M_lds[2048];    // padding mask row (exp2 domain) for this batch
  const int bh = blockIdx.x;
  const int slot = blockIdx.y;
  const int b = bh >> 4, h = bh & 15;
  const int tid=threadIdx.x, lane=tid&63, wid=tid>>6;
  const int l31 = lane&31, hi = lane>>5;
  const u16* Qh = Qp + (size_t)bh*CL*CD;
  const u16* Kh = Kp + (size_t)bh*CL*CD;
  const u16* Vhd = Vt + (size_t)(h*CD)*CM + b*CL;

  // stage padding-mask row once (8KB). Issued FIRST so the t=0 vmcnt(8) covers it.
  #pragma unroll
  for (int i=0;i<2;i++)
    __builtin_amdgcn_global_load_lds(GP(maskf + b*CL + (i*256+tid)*4),
                                     LP(&M_lds[(i*256+tid)*4]), 16, 0, 0);

  auto STAGE = [&](int t, int buf){   // 4 gload_lds instructions per wave
    const u16* Ksrc = Kh + t*64*CD;
    const u16* Vsrc = Vhd + t*64;
    #pragma unroll
    for (int i=0;i<2;i++){
      int c = tid + i*256;
      int row = c>>3, sc = c&7;
      int c16 = sc ^ (row&7);
      __builtin_amdgcn_global_load_lds(GP(Ksrc + row*CD + c16*8),
                                       LP(&K_lds[buf][c*8]), 16, 0, 0);
      __builtin_amdgcn_global_load_lds(GP(Vsrc + (size_t)row*CM + c16*8),
                                       LP(&V_lds[buf][c*8]), 16, 0, 0);
    }
  };

  const int rowb = l31*128;            // LDS row byte base
  const int rsw  = (l31&7)<<4;
  const int qts2[2] = {15-slot, slot};

  for (int qi=0; qi<2; qi++){
    const int qt = qts2[qi];
    const int qw0 = qt*128 + wid*32;
    const int qlane = qw0 + l31;

    bf16x8 qf[4];
    #pragma unroll
    for (int c=0;c<4;c++)
      qf[c] = as_bf(*(const uint4*)(Qh + (size_t)qlane*CD + c*16 + hi*8));

    f32x16 o0 = {}, o1 = {};
    float m_r = -3e38f, l_r = 0.f;

    const int nt = qt*2 + 2;
    STAGE(0,0); STAGE(1,1);

    for (int t=0; t<nt; t++){
      // vmcnt ledger: entering iter t, {S(t),S(t+1)} = 8 outstanding (each 4/wave)
      if (t+2 < nt){ STAGE(t+2,(t+2)&3); WAITB("8"); }
      else if (t+1 < nt){ WAITB("4"); }
      else { WAITB("0"); }

      const int kv0 = t*64;
      const char* kb = (const char*)K_lds[t&3];
      const char* vb = (const char*)V_lds[t&3];

      // ---- padding mask (broadcast LDS reads; issue early to overlap MFMA)
      f32x4 cm[8];
      #pragma unroll
      for (int s2=0;s2<2;s2++)
        #pragma unroll
        for (int g=0; g<4; g++)
          cm[s2*4+g] = *(const f32x4*)&M_lds[kv0 + s2*32 + g*8 + hi*4];

      // ---- S^T = K @ Q^T  (two 32x32 tiles over kv); Q carries 0.125*log2e
      f32x16 s0 = {}, s1 = {};
      __builtin_amdgcn_s_setprio(1);
      #pragma unroll
      for (int c=0;c<4;c++){
        int cb = (c*32 + hi*16) ^ rsw;
        bf16x8 k0 = as_bf(*(const uint4*)(kb + rowb + cb));
        bf16x8 k1 = as_bf(*(const uint4*)(kb + 4096 + rowb + cb));
        s0 = __builtin_amdgcn_mfma_f32_32x32x16_bf16(k0, qf[c], s0, 0,0,0);
        s1 = __builtin_amdgcn_mfma_f32_32x32x16_bf16(k1, qf[c], s1, 0,0,0);
      }
      __builtin_amdgcn_s_setprio(0);

      // ---- v = s + mask (+ causal on diagonal tiles), in place (exp2 domain)
      if (kv0 + 63 > qw0){
        #pragma unroll
        for (int s2=0;s2<2;s2++){
          f32x16& sv = s2 ? s1 : s0;
          #pragma unroll
          for (int reg=0; reg<16; reg++){
            int k = kv0 + s2*32 + (reg&3) + (reg>>2)*8 + hi*4;
            float v = sv[reg] + cm[s2*4+(reg>>2)][reg&3];
            sv[reg] = (k > qlane) ? v + NEGBIG : v;
          }
        }
      } else {
        #pragma unroll
        for (int s2=0;s2<2;s2++){
          f32x16& sv = s2 ? s1 : s0;
          #pragma unroll
          for (int reg=0; reg<16; reg++)
            sv[reg] = sv[reg] + cm[s2*4+(reg>>2)][reg&3];
        }
      }

      // ---- row max (pairwise + v_max3 tree + partner swap)
      f32x16 mx;
      #pragma unroll
      for (int r=0;r<16;r++) mx[r] = fmaxf(s0[r], s1[r]);
      float a0 = max3f(mx[0],mx[1],mx[2]);
      float a1 = max3f(mx[3],mx[4],mx[5]);
      float a2 = max3f(mx[6],mx[7],mx[8]);
      float a3 = max3f(mx[9],mx[10],mx[11]);
      float a4 = max3f(mx[12],mx[13],mx[14]);
      float vmax = fmaxf(max3f(a0,a1,a2), max3f(a3,a4,mx[15]));
      vmax = fmaxf(vmax, __shfl_xor(vmax, 32));

      // ---- defer-max (T13): rescale only when max grew by > THR (log2 units)
      if (__any(vmax > m_r + 12.0f)){
        float mnew = fmaxf(m_r, vmax);
        float sc = fexp2(m_r - mnew);
        l_r *= sc;
        o0 *= sc; o1 *= sc;
        m_r = mnew;
      }

      // ---- p = exp2(v - m), in place (p <= 2^12)
      #pragma unroll
      for (int r=0;r<16;r++){
        s0[r] = fexp2(s0[r] - m_r);
        s1[r] = fexp2(s1[r] - m_r);
      }
      // ---- row sum
      f32x16 sm = s0 + s1;
      #pragma unroll
      for (int w=8; w>=1; w>>=1)
        #pragma unroll
        for (int r=0;r<w;r++) sm[r] = sm[r] + sm[r+w];
      float rsum = sm[0];
      rsum += __shfl_xor(rsum, 32);
      l_r += rsum;

      // ---- P -> bf16 B-fragments in-register (cvt_pk + permlane32_swap)
      u32 w_[16];
      #pragma unroll
      for (int s2=0;s2<2;s2++){
        f32x16& sv = s2 ? s1 : s0;
        #pragma unroll
        for (int c=0;c<2;c++){
          u32 a  = cvt_pk(sv[c*8+0], sv[c*8+1]);
          u32 bb = cvt_pk(sv[c*8+2], sv[c*8+3]);
          u32 cc = cvt_pk(sv[c*8+4], sv[c*8+5]);
          u32 dd = cvt_pk(sv[c*8+6], sv[c*8+7]);
          plswap(a, cc); plswap(bb, dd);
          int base = (s2*2+c)*4;
          w_[base+0]=a; w_[base+1]=bb; w_[base+2]=cc; w_[base+3]=dd;
        }
      }

      // ---- O^T += V^T @ P^T
      __builtin_amdgcn_s_setprio(1);
      #pragma unroll
      for (int kc=0; kc<4; kc++){
        bf16x8 pf = as_bf(make_uint4(w_[kc*4], w_[kc*4+1], w_[kc*4+2], w_[kc*4+3]));
        int cb = (kc*32 + hi*16) ^ rsw;
        bf16x8 v0 = as_bf(*(const uint4*)(vb + rowb + cb));
        bf16x8 v1 = as_bf(*(const uint4*)(vb + 4096 + rowb + cb));
        o0 = __builtin_amdgcn_mfma_f32_32x32x16_bf16(v0, pf, o0, 0,0,0);
        o1 = __builtin_amdgcn_mfma_f32_32x32x16_bf16(v1, pf, o1, 0,0,0);
      }
      __builtin_amdgcn_s_setprio(0);
      // no trailing barrier: ring depth 4 + per-iter barrier bounds wave skew safely
    }

    // ---- normalize + write O^T: lane has q=qlane, d = mt*32 + g*8 + hi*4 + {0..3}
    float inv = 1.f / l_r;
    u16* dst = AO + (size_t)(b*CL + qlane)*CE + h*CD;
    #pragma unroll
    for (int mt=0; mt<2; mt++){
      f32x16& ov = mt ? o1 : o0;
      #pragma unroll
      for (int g=0; g<4; g++){
        u32 lo  = cvt_pk(ov[g*4+0]*inv, ov[g*4+1]*inv);
        u32 hi2 = cvt_pk(ov[g*4+2]*inv, ov[g*4+3]*inv);
        *(uint2*)(dst + mt*32 + g*8 + hi*4) = make_uint2(lo, hi2);
      }
    }
    // drain + protect ring reuse by qi=1 prologue (and reset vmcnt ledger)
    __syncthreads();
  }
}

// ---------------- launcher ----------------
extern "C" void kernel_launch(void* const* d_in, const int* in_sizes, int n_in,
                              void* d_out, int out_size, void* d_ws, size_t ws_size,
                              hipStream_t stream) {
  const float* query = (const float*)d_in[0];
  const float* key_  = (const float*)d_in[1];
  const float* value = (const float*)d_in[2];
  const float* wq = (const float*)d_in[3];
  const float* bq = (const float*)d_in[4];
  const float* wk = (const float*)d_in[5];
  const float* bk = (const float*)d_in[6];
  const float* wv = (const float*)d_in[7];
  const float* bv = (const float*)d_in[8];
  const float* wo = (const float*)d_in[9];
  const float* bo = (const float*)d_in[10];
  const void*  kpm = d_in[11];

  char* ws = (char*)d_ws;
  constexpr size_t SZ_ME_BF = (size_t)CM*CE*2;    // 16 MiB
  constexpr size_t SZ_EE_BF = (size_t)CE*CE*2;    // 2 MiB
  constexpr size_t OFF_FLAG = 0;
  constexpr size_t OFF_MASKF= 256;
  constexpr size_t OFF_B0   = 65536;              // qbf; later AO
  constexpr size_t OFF_B1   = OFF_B0 + SZ_ME_BF;  // kbf
  constexpr size_t OFF_B2   = OFF_B1 + SZ_ME_BF;  // vbf; later Qp (2-launch path)
  constexpr size_t OFF_WQ   = OFF_B2 + SZ_ME_BF;
  constexpr size_t OFF_WK   = OFF_WQ + SZ_EE_BF;
  constexpr size_t OFF_WV   = OFF_WK + SZ_EE_BF;
  constexpr size_t OFF_WO   = OFF_WV + SZ_EE_BF;
  constexpr size_t OFF_KP   = OFF_WO + SZ_EE_BF;  // Kp
  constexpr size_t OFF_VT   = OFF_KP + SZ_ME_BF;  // Vt [1024][8192]
  constexpr size_t OFF_QP   = OFF_VT + SZ_ME_BF;  // optional dedicated Qp

  int*   flag  = (int*)(ws + OFF_FLAG);
  float* maskf = (float*)(ws + OFF_MASKF);
  u16*  qbf = (u16*)(ws + OFF_B0);
  u16*  kbf = (u16*)(ws + OFF_B1);
  u16*  vbf = (u16*)(ws + OFF_B2);
  u16*  wqb = (u16*)(ws + OFF_WQ);
  u16*  wkb = (u16*)(ws + OFF_WK);
  u16*  wvb = (u16*)(ws + OFF_WV);
  u16*  wob = (u16*)(ws + OFF_WO);
  u16*  Kp  = (u16*)(ws + OFF_KP);
  u16*  Vt  = (u16*)(ws + OFF_VT);
  u16*  AO  = qbf;                   // alias: qbf dead after Q projection

  detect_mask_kernel<<<1,256,0,stream>>>(kpm, flag);
  convert_mask_kernel<<<(CB*CL+255)/256,256,0,stream>>>(kpm, flag, maskf);

  cast_all<<<28672,256,0,stream>>>(query, key_, value, wq, wk, wv, wo,
                                   qbf, kbf, vbf, wqb, wkb, wvb, wob);

  u16* Qp;
  if (ws_size >= OFF_QP + SZ_ME_BF){
    // dedicated Qp buffer: all three projections in one launch (no alias hazard)
    Qp = (u16*)(ws + OFF_QP);
    gemm_qkv<<<dim3(128,3),512,0,stream>>>(qbf, kbf, vbf, wqb, wkb, wvb,
                                           bq, bk, bv, Qp, Kp, Vt, 0);
  } else {
    // fallback: Qp aliases vbf -> V (and K) must complete before Q projection
    Qp = vbf;
    gemm_qkv<<<dim3(128,2),512,0,stream>>>(qbf, kbf, vbf, wqb, wkb, wvb,
                                           bq, bk, bv, Qp, Kp, Vt, 1);
    gemm_qkv<<<dim3(128,1),512,0,stream>>>(qbf, kbf, vbf, wqb, wkb, wvb,
                                           bq, bk, bv, Qp, Kp, Vt, 0);
  }

  attn_kernel<<<dim3(CB*CH, 8),256,0,stream>>>(Qp, Kp, Vt, maskf, AO);

  gemm_out<<<512,256,0,stream>>>(AO, wob, bo, (float*)d_out);
}